// Round 3
// baseline (110.289 us; speedup 1.0000x reference)
//
#include <hip/hip_runtime.h>

#define NB 8
#define LEN 256
#define DIM 768
#define NC 3976
// output layout (floats): fofe_codes [8][3976][5][768] = 122142720,
// cands_pos [8][3976][2] = 63616, padded [8][3976] = 31808
#define OFF_POS 122142720
#define OFF_PAD (122142720 + 63616)

constexpr float ALPHA_F = 0.9f;
constexpr float A32 = 0.03433683820292512f;  // 0.9^32

typedef float f4 __attribute__((ext_vector_type(4)));

// Prefix/suffix geometric scan: P[l] = x[l] + a*P[l-1], S[l] = x[l] + a*S[l+1].
// block = 256 threads: 32 d-lanes x 8 l-chunks (32 elems each).
// grid = (DIM/32 = 24, NB, 2 directions)
__global__ __launch_bounds__(256) void scan_kernel(const float* __restrict__ x,
                                                   float* __restrict__ P,
                                                   float* __restrict__ S) {
    const int dl = threadIdx.x & 31;
    const int chunk = threadIdx.x >> 5;
    const int d = blockIdx.x * 32 + dl;
    const int b = blockIdx.y;
    const int dir = blockIdx.z;
    const float* __restrict__ xb = x + (size_t)b * LEN * DIM;
    float* __restrict__ ob = (dir ? S : P) + (size_t)b * LEN * DIM;

    float vals[32];
    float acc = 0.f;
#pragma unroll
    for (int t = 0; t < 32; ++t) {
        const int lm = chunk * 32 + t;
        const int l = dir ? (LEN - 1 - lm) : lm;
        acc = fmaf(ALPHA_F, acc, xb[l * DIM + d]);
        vals[t] = acc;
    }

    __shared__ float ends[8][32];
    ends[chunk][dl] = acc;
    __syncthreads();

    // carry into this chunk: C_k = end[k-1] + a^32 * C_{k-1}
    float carry = 0.f;
    for (int k = 0; k < chunk; ++k)
        carry = fmaf(A32, carry, ends[k][dl]);

    float w = ALPHA_F;
#pragma unroll
    for (int t = 0; t < 32; ++t) {
        const int lm = chunk * 32 + t;
        const int l = dir ? (LEN - 1 - lm) : lm;
        ob[l * DIM + d] = fmaf(w, carry, vals[t]);
        w *= ALPHA_F;
    }
}

// One 192-thread block per (batch, start i); loops over the <=16 spans.
// grid = (NB, LEN): blockIdx.x = batch -> round-robin XCD dispatch pins each
// batch's 3.1 MB P/S working set to one XCD's 4 MiB L2.
__global__ __launch_bounds__(192) void out_kernel(const float* __restrict__ P,
                                                  const float* __restrict__ S,
                                                  const int* __restrict__ mask,
                                                  float* __restrict__ out) {
    const int b = blockIdx.x;
    const int i = blockIdx.y;
    const int t = threadIdx.x;

    // span count n and candidate base index c0 for this start
    int n, c0;
    if (i <= 240) {
        n = 16;
        c0 = i * 16;
    } else {
        const int r = LEN - i;           // 15..1
        n = r;
        c0 = 3856 + 120 - r * (r + 1) / 2;
    }

    const f4 z4 = (f4)0.f;
    const f4* __restrict__ Pb = (const f4*)(P + (size_t)b * LEN * DIM);
    const f4* __restrict__ Sb = (const f4*)(S + (size_t)b * LEN * DIM);

    // start-invariant rows: load once, reuse for all spans
    const f4 pm1 = (i > 0) ? Pb[(i - 1) * 192 + t] : z4;  // left excl
    const f4 si = Sb[i * 192 + t];                        // right incl

    f4* o = (f4*)out + (size_t)(b * NC + c0) * 960 + t;
    float w = ALPHA_F;  // alpha^(s+1)
    for (int s = 0; s < n; ++s) {
        const int e = i + s;
        const f4 pe = Pb[e * 192 + t];                              // left incl
        const f4 se1 = (e < LEN - 1) ? Sb[(e + 1) * 192 + t] : z4;  // right excl
        const f4 cand = pe - w * pm1;

        // fofe_codes is write-once: nt stores keep L2/L3 for P/S
        __builtin_nontemporal_store(pm1, o + 0 * 192);
        __builtin_nontemporal_store(pe, o + 1 * 192);
        __builtin_nontemporal_store(cand, o + 2 * 192);
        __builtin_nontemporal_store(si, o + 3 * 192);
        __builtin_nontemporal_store(se1, o + 4 * 192);
        o += 960;
        w *= ALPHA_F;
    }

    if (t < 64) {  // wave 0: cands_pos + padded_cands for all n candidates
        const int m = (t < n) ? mask[b * LEN + i + t] : 0;
        const unsigned long long ball = __ballot(m != 0);
        if (t < n) {
            const size_t c = (size_t)(b * NC + c0 + t);
            out[OFF_POS + c * 2] = (float)i;
            out[OFF_POS + c * 2 + 1] = (float)(i + t);
            // window [i, i+t]: any mask bit among ballot bits 0..t
            out[OFF_PAD + c] = (ball & ((2ull << t) - 1)) ? 1.f : 0.f;
        }
    }
}

extern "C" void kernel_launch(void* const* d_in, const int* in_sizes, int n_in,
                              void* d_out, int out_size, void* d_ws, size_t ws_size,
                              hipStream_t stream) {
    const float* x = (const float*)d_in[0];
    const int* mask = (const int*)d_in[1];
    float* out = (float*)d_out;
    float* P = (float*)d_ws;                  // [8][256][768] fp32
    float* S = P + (size_t)NB * LEN * DIM;    // [8][256][768] fp32  (12.6 MB total)

    scan_kernel<<<dim3(DIM / 32, NB, 2), 256, 0, stream>>>(x, P, S);
    out_kernel<<<dim3(NB, LEN), 192, 0, stream>>>(P, S, mask, out);
}

// Round 4
// 108.824 us; speedup vs baseline: 1.0135x; 1.0135x over previous
//
#include <hip/hip_runtime.h>

#define NB 8
#define LEN 256
#define DIM 768
#define NC 3976
// output layout (floats): fofe_codes [8][3976][5][768] = 122142720,
// cands_pos [8][3976][2] = 63616, padded [8][3976] = 31808
#define OFF_POS 122142720
#define OFF_PAD (122142720 + 63616)
#define G 4        // starts per block
#define KTRUNC 64  // alpha^64 = 1.18e-3; truncation error ~1e-2 << 5.1 threshold

constexpr float ALPHA_F = 0.9f;

typedef float f4 __attribute__((ext_vector_type(4)));

// One fused kernel: each block (batch b, starts i0..i0+3) recomputes the
// truncated prefix/suffix geometric scans it needs from x (L2-resident),
// keeps the 40 needed rows in registers, then streams NT stores.
// grid = (NB, LEN/G); blockIdx.x = b -> round-robin XCD dispatch pins each
// batch's 786 KB x slice to one XCD's L2.
__global__ __launch_bounds__(192, 2) void fused_kernel(const float* __restrict__ x,
                                                       const int* __restrict__ mask,
                                                       float* __restrict__ out) {
    const int b = blockIdx.x;
    const int i0 = blockIdx.y * G;
    const int t = threadIdx.x;
    const f4* __restrict__ xb = (const f4*)(x + (size_t)b * LEN * DIM);  // row l: [l*192 + t]

    // ---- forward scan: retain P rows l = i0-1 .. i0+G+14  (rows r = l-(i0-1)) ----
    f4 P[G + 16];
    f4 acc = (f4)0.f;
    {
        int l0 = i0 - 1 - KTRUNC;
        if (l0 < 0) l0 = 0;
#pragma unroll 8
        for (int l = l0; l <= i0 - 2; ++l)  // warmup (truncated), no retention
            acc = acc * ALPHA_F + xb[l * 192 + t];
#pragma unroll
        for (int r = 0; r < G + 16; ++r) {
            const int l = i0 - 1 + r;
            if (l >= 0 && l < LEN) acc = acc * ALPHA_F + xb[l * 192 + t];
            P[r] = acc;  // for i0=0, r=0 -> P[-1] = 0 (acc untouched)
        }
    }

    // ---- backward scan: retain S rows l = i0 .. i0+G+15 (rows r = l-i0) ----
    f4 S[G + 16];
    acc = (f4)0.f;
    {
        int l1 = i0 + G + 15 + KTRUNC;
        if (l1 > LEN - 1) l1 = LEN - 1;
#pragma unroll 8
        for (int l = l1; l > i0 + G + 15; --l)  // warmup (truncated)
            acc = acc * ALPHA_F + xb[l * 192 + t];
#pragma unroll
        for (int r = G + 15; r >= 0; --r) {
            const int l = i0 + r;
            if (l < LEN) {
                acc = acc * ALPHA_F + xb[l * 192 + t];
                S[r] = acc;
            } else {
                S[r] = (f4)0.f;  // right context beyond doc end = 0
            }
        }
    }

    // ---- store phase: pure NT-store stream ----
#pragma unroll
    for (int g = 0; g < G; ++g) {
        const int i = i0 + g;
        int n, c0;
        if (i <= LEN - 16) {
            n = 16;
            c0 = i * 16;
        } else {
            const int r = LEN - i;  // 15..1
            n = r;
            c0 = 3856 + 120 - r * (r + 1) / 2;
        }
        const f4 pm1 = P[g];  // P[i-1]  (left excl)
        const f4 si = S[g];   // S[i]    (right incl)

        f4* o = (f4*)out + (size_t)(b * NC + c0) * 960 + t;
        float w = ALPHA_F;  // alpha^(s+1)
#pragma unroll
        for (int s = 0; s < 16; ++s) {
            if (s < n) {
                const f4 pe = P[g + 1 + s];   // P[e],   e = i+s
                const f4 se1 = S[g + 1 + s];  // S[e+1] (0 past doc end)
                const f4 cand = pe - w * pm1;
                __builtin_nontemporal_store(pm1, o + 0 * 192);
                __builtin_nontemporal_store(pe, o + 1 * 192);
                __builtin_nontemporal_store(cand, o + 2 * 192);
                __builtin_nontemporal_store(si, o + 3 * 192);
                __builtin_nontemporal_store(se1, o + 4 * 192);
                o += 960;
            }
            w *= ALPHA_F;
        }

        if (t < 64) {  // wave 0: cands_pos + padded_cands
            const int m = (t < n) ? mask[b * LEN + i + t] : 0;
            const unsigned long long ball = __ballot(m != 0);
            if (t < n) {
                const size_t c = (size_t)(b * NC + c0 + t);
                out[OFF_POS + c * 2] = (float)i;
                out[OFF_POS + c * 2 + 1] = (float)(i + t);
                // window [i, i+t]: any mask bit among ballot bits 0..t
                out[OFF_PAD + c] = (ball & ((2ull << t) - 1)) ? 1.f : 0.f;
            }
        }
    }
}

extern "C" void kernel_launch(void* const* d_in, const int* in_sizes, int n_in,
                              void* d_out, int out_size, void* d_ws, size_t ws_size,
                              hipStream_t stream) {
    const float* x = (const float*)d_in[0];
    const int* mask = (const int*)d_in[1];
    float* out = (float*)d_out;
    fused_kernel<<<dim3(NB, LEN / G), 192, 0, stream>>>(x, mask, out);
}

// Round 5
// 107.364 us; speedup vs baseline: 1.0272x; 1.0136x over previous
//
#include <hip/hip_runtime.h>

#define NB 8
#define LEN 256
#define DIM 768
#define NC 3976
// output layout (floats): fofe_codes [8][3976][5][768] = 122142720,
// cands_pos [8][3976][2] = 63616, padded [8][3976] = 31808
#define OFF_POS 122142720
#define OFF_PAD (122142720 + 63616)
#define G 4        // starts per block
#define KTRUNC 64  // alpha^64 = 1.18e-3; truncation error ~1e-2 << 5.1 threshold

constexpr float ALPHA_F = 0.9f;

typedef float f4 __attribute__((ext_vector_type(4)));

// One fused kernel: each block (batch b, starts i0..i0+3) recomputes the
// truncated prefix/suffix geometric scans it needs from x (L2-resident),
// keeps the 40 needed rows in registers, then streams plain stores.
// A/B vs R4: ONLY change is nontemporal -> plain stores. NT bypasses L2 and
// stalls the CU store queue on far-memory latency at 6 waves/CU; plain stores
// retire into write-back L2 (the 6.9 TB/s fill-kernel path).
// grid = (NB, LEN/G); blockIdx.x = b -> round-robin XCD dispatch pins each
// batch's 786 KB x slice to one XCD's L2.
__global__ __launch_bounds__(192, 2) void fused_kernel(const float* __restrict__ x,
                                                       const int* __restrict__ mask,
                                                       float* __restrict__ out) {
    const int b = blockIdx.x;
    const int i0 = blockIdx.y * G;
    const int t = threadIdx.x;
    const f4* __restrict__ xb = (const f4*)(x + (size_t)b * LEN * DIM);  // row l: [l*192 + t]

    // ---- forward scan: retain P rows l = i0-1 .. i0+G+14  (rows r = l-(i0-1)) ----
    f4 P[G + 16];
    f4 acc = (f4)0.f;
    {
        int l0 = i0 - 1 - KTRUNC;
        if (l0 < 0) l0 = 0;
#pragma unroll 8
        for (int l = l0; l <= i0 - 2; ++l)  // warmup (truncated), no retention
            acc = acc * ALPHA_F + xb[l * 192 + t];
#pragma unroll
        for (int r = 0; r < G + 16; ++r) {
            const int l = i0 - 1 + r;
            if (l >= 0 && l < LEN) acc = acc * ALPHA_F + xb[l * 192 + t];
            P[r] = acc;  // for i0=0, r=0 -> P[-1] = 0 (acc untouched)
        }
    }

    // ---- backward scan: retain S rows l = i0 .. i0+G+15 (rows r = l-i0) ----
    f4 S[G + 16];
    acc = (f4)0.f;
    {
        int l1 = i0 + G + 15 + KTRUNC;
        if (l1 > LEN - 1) l1 = LEN - 1;
#pragma unroll 8
        for (int l = l1; l > i0 + G + 15; --l)  // warmup (truncated)
            acc = acc * ALPHA_F + xb[l * 192 + t];
#pragma unroll
        for (int r = G + 15; r >= 0; --r) {
            const int l = i0 + r;
            if (l < LEN) {
                acc = acc * ALPHA_F + xb[l * 192 + t];
                S[r] = acc;
            } else {
                S[r] = (f4)0.f;  // right context beyond doc end = 0
            }
        }
    }

    // ---- store phase: pure store stream through L2 ----
#pragma unroll
    for (int g = 0; g < G; ++g) {
        const int i = i0 + g;
        int n, c0;
        if (i <= LEN - 16) {
            n = 16;
            c0 = i * 16;
        } else {
            const int r = LEN - i;  // 15..1
            n = r;
            c0 = 3856 + 120 - r * (r + 1) / 2;
        }
        const f4 pm1 = P[g];  // P[i-1]  (left excl)
        const f4 si = S[g];   // S[i]    (right incl)

        f4* o = (f4*)out + (size_t)(b * NC + c0) * 960 + t;
        float w = ALPHA_F;  // alpha^(s+1)
#pragma unroll
        for (int s = 0; s < 16; ++s) {
            if (s < n) {
                const f4 pe = P[g + 1 + s];   // P[e],   e = i+s
                const f4 se1 = S[g + 1 + s];  // S[e+1] (0 past doc end)
                const f4 cand = pe - w * pm1;
                o[0 * 192] = pm1;
                o[1 * 192] = pe;
                o[2 * 192] = cand;
                o[3 * 192] = si;
                o[4 * 192] = se1;
                o += 960;
            }
            w *= ALPHA_F;
        }

        if (t < 64) {  // wave 0: cands_pos + padded_cands
            const int m = (t < n) ? mask[b * LEN + i + t] : 0;
            const unsigned long long ball = __ballot(m != 0);
            if (t < n) {
                const size_t c = (size_t)(b * NC + c0 + t);
                out[OFF_POS + c * 2] = (float)i;
                out[OFF_POS + c * 2 + 1] = (float)(i + t);
                // window [i, i+t]: any mask bit among ballot bits 0..t
                out[OFF_PAD + c] = (ball & ((2ull << t) - 1)) ? 1.f : 0.f;
            }
        }
    }
}

extern "C" void kernel_launch(void* const* d_in, const int* in_sizes, int n_in,
                              void* d_out, int out_size, void* d_ws, size_t ws_size,
                              hipStream_t stream) {
    const float* x = (const float*)d_in[0];
    const int* mask = (const int*)d_in[1];
    float* out = (float*)d_out;
    fused_kernel<<<dim3(NB, LEN / G), 192, 0, stream>>>(x, mask, out);
}

// Round 6
// 104.967 us; speedup vs baseline: 1.0507x; 1.0228x over previous
//
#include <hip/hip_runtime.h>

#define NB 8
#define LEN 256
#define DIM 768
#define NC 3976
// output layout (floats): fofe_codes [8][3976][5][768] = 122142720,
// cands_pos [8][3976][2] = 63616, padded [8][3976] = 31808
#define OFF_POS 122142720
#define OFF_PAD (122142720 + 63616)

constexpr float ALPHA_F = 0.9f;
constexpr float A32 = 0.03433683820292512f;  // 0.9^32

typedef float f4 __attribute__((ext_vector_type(4)));

// Prefix/suffix geometric scan: P[l] = x[l] + a*P[l-1], S[l] = x[l] + a*S[l+1].
// block = 256 threads: 32 d-lanes x 8 l-chunks (32 elems each).
// grid = (DIM/32 = 24, NB, 2 directions)
__global__ __launch_bounds__(256) void scan_kernel(const float* __restrict__ x,
                                                   float* __restrict__ P,
                                                   float* __restrict__ S) {
    const int dl = threadIdx.x & 31;
    const int chunk = threadIdx.x >> 5;
    const int d = blockIdx.x * 32 + dl;
    const int b = blockIdx.y;
    const int dir = blockIdx.z;
    const float* __restrict__ xb = x + (size_t)b * LEN * DIM;
    float* __restrict__ ob = (dir ? S : P) + (size_t)b * LEN * DIM;

    float vals[32];
    float acc = 0.f;
#pragma unroll
    for (int t = 0; t < 32; ++t) {
        const int lm = chunk * 32 + t;
        const int l = dir ? (LEN - 1 - lm) : lm;
        acc = fmaf(ALPHA_F, acc, xb[l * DIM + d]);
        vals[t] = acc;
    }

    __shared__ float ends[8][32];
    ends[chunk][dl] = acc;
    __syncthreads();

    // carry into this chunk: C_k = end[k-1] + a^32 * C_{k-1}
    float carry = 0.f;
    for (int k = 0; k < chunk; ++k)
        carry = fmaf(A32, carry, ends[k][dl]);

    float w = ALPHA_F;
#pragma unroll
    for (int t = 0; t < 32; ++t) {
        const int lm = chunk * 32 + t;
        const int l = dir ? (LEN - 1 - lm) : lm;
        ob[l * DIM + d] = fmaf(w, carry, vals[t]);
        w *= ALPHA_F;
    }
}

// Store kernel: one 192-thread block per (batch, start i); minimal VGPR so
// occupancy is high (launch_bounds caps at 64 VGPR -> ~15 waves/CU resident,
// 2.5x the fused R5 version). pe/se1 stream from XCD-pinned L2.
// grid = (NB, LEN): blockIdx.x = b keeps each batch's 3.1 MB P/S slice on one
// XCD's 4 MiB L2.
__global__ __launch_bounds__(192, 4) void out_kernel(const float* __restrict__ P,
                                                     const float* __restrict__ S,
                                                     const int* __restrict__ mask,
                                                     float* __restrict__ out) {
    const int b = blockIdx.x;
    const int i = blockIdx.y;
    const int t = threadIdx.x;

    // span count n and candidate base index c0 for this start
    int n, c0;
    if (i <= 240) {
        n = 16;
        c0 = i * 16;
    } else {
        const int r = LEN - i;  // 15..1
        n = r;
        c0 = 3856 + 120 - r * (r + 1) / 2;
    }

    const f4 z4 = (f4)0.f;
    const f4* __restrict__ Pb = (const f4*)(P + (size_t)b * LEN * DIM);
    const f4* __restrict__ Sb = (const f4*)(S + (size_t)b * LEN * DIM);

    // start-invariant rows: load once, reuse for all spans
    const f4 pm1 = (i > 0) ? Pb[(i - 1) * 192 + t] : z4;  // left excl
    const f4 si = Sb[i * 192 + t];                        // right incl

    f4* o = (f4*)out + (size_t)(b * NC + c0) * 960 + t;
    float w = ALPHA_F;  // alpha^(s+1)
    for (int s = 0; s < n; ++s) {
        const int e = i + s;
        const f4 pe = Pb[e * 192 + t];                              // left incl
        const f4 se1 = (e < LEN - 1) ? Sb[(e + 1) * 192 + t] : z4;  // right excl
        const f4 cand = pe - w * pm1;
        o[0 * 192] = pm1;  // [left_excl, left_incl, cand, right_incl, right_excl]
        o[1 * 192] = pe;
        o[2 * 192] = cand;
        o[3 * 192] = si;
        o[4 * 192] = se1;
        o += 960;
        w *= ALPHA_F;
    }

    if (t < 64) {  // wave 0: cands_pos + padded_cands for all n candidates
        const int m = (t < n) ? mask[b * LEN + i + t] : 0;
        const unsigned long long ball = __ballot(m != 0);
        if (t < n) {
            const size_t c = (size_t)(b * NC + c0 + t);
            out[OFF_POS + c * 2] = (float)i;
            out[OFF_POS + c * 2 + 1] = (float)(i + t);
            // window [i, i+t]: any mask bit among ballot bits 0..t
            out[OFF_PAD + c] = (ball & ((2ull << t) - 1)) ? 1.f : 0.f;
        }
    }
}

extern "C" void kernel_launch(void* const* d_in, const int* in_sizes, int n_in,
                              void* d_out, int out_size, void* d_ws, size_t ws_size,
                              hipStream_t stream) {
    const float* x = (const float*)d_in[0];
    const int* mask = (const int*)d_in[1];
    float* out = (float*)d_out;
    float* P = (float*)d_ws;                  // [8][256][768] fp32
    float* S = P + (size_t)NB * LEN * DIM;    // [8][256][768] fp32  (12.6 MB total)

    scan_kernel<<<dim3(DIM / 32, NB, 2), 256, 0, stream>>>(x, P, S);
    out_kernel<<<dim3(NB, LEN), 192, 0, stream>>>(P, S, mask, out);
}

// Round 7
// 102.023 us; speedup vs baseline: 1.0810x; 1.0289x over previous
//
#include <hip/hip_runtime.h>

#define NB 8
#define LEN 256
#define DIM 768
#define NC 3976
// output layout (floats): fofe_codes [8][3976][5][768] = 122142720,
// cands_pos [8][3976][2] = 63616, padded [8][3976] = 31808
#define OFF_POS 122142720
#define OFF_PAD (122142720 + 63616)
#define NROWS (NB * NC * 5)        // 159040 fofe rows of 768 floats
#define NVROWS (NROWS + NB * LEN)  // + 2048 virtual rows for pos/pad
#define NBLK 2048

constexpr float ALPHA_F = 0.9f;
constexpr float A32 = 0.03433683820292512f;  // 0.9^32

typedef float f4 __attribute__((ext_vector_type(4)));

__device__ __constant__ float APOW[17] = {
    1.f, 0.9f, 0.81f, 0.729f, 0.6561f, 0.59049f, 0.531441f, 0.4782969f,
    0.43046721f, 0.387420489f, 0.3486784401f, 0.31381059609f, 0.282429536481f,
    0.2541865828329f, 0.22876792454961f, 0.205891132094649f, 0.1853020188851841f};

// Prefix/suffix geometric scan: P[l] = x[l] + a*P[l-1], S[l] = x[l] + a*S[l+1].
// block = 256 threads: 32 d-lanes x 8 l-chunks (32 elems each).
// grid = (DIM/32 = 24, NB, 2 directions)
__global__ __launch_bounds__(256) void scan_kernel(const float* __restrict__ x,
                                                   float* __restrict__ P,
                                                   float* __restrict__ S) {
    const int dl = threadIdx.x & 31;
    const int chunk = threadIdx.x >> 5;
    const int d = blockIdx.x * 32 + dl;
    const int b = blockIdx.y;
    const int dir = blockIdx.z;
    const float* __restrict__ xb = x + (size_t)b * LEN * DIM;
    float* __restrict__ ob = (dir ? S : P) + (size_t)b * LEN * DIM;

    float vals[32];
    float acc = 0.f;
#pragma unroll
    for (int t = 0; t < 32; ++t) {
        const int lm = chunk * 32 + t;
        const int l = dir ? (LEN - 1 - lm) : lm;
        acc = fmaf(ALPHA_F, acc, xb[l * DIM + d]);
        vals[t] = acc;
    }

    __shared__ float ends[8][32];
    ends[chunk][dl] = acc;
    __syncthreads();

    // carry into this chunk: C_k = end[k-1] + a^32 * C_{k-1}
    float carry = 0.f;
    for (int k = 0; k < chunk; ++k)
        carry = fmaf(A32, carry, ends[k][dl]);

    float w = ALPHA_F;
#pragma unroll
    for (int t = 0; t < 32; ++t) {
        const int lm = chunk * 32 + t;
        const int l = dir ? (LEN - 1 - lm) : lm;
        ob[l * DIM + d] = fmaf(w, carry, vals[t]);
        w *= ALPHA_F;
    }
}

// Grid-stride ROW SWEEP (fill-kernel-mimicking write pattern): at step q all
// NBLK blocks write rows q*NBLK..q*NBLK+NBLK-1 — a contiguous ~6 MB window
// advancing linearly through the 489 MB output (DRAM row locality like the
// 6.9 TB/s fillBuffer). One 3072 B row per block per step (192 lanes x 16 B).
// Sources are 1-2 P/S rows (12.6 MB total, L3-resident), decode wave-uniform.
__global__ __launch_bounds__(192) void row_kernel(const float* __restrict__ P,
                                                  const float* __restrict__ S,
                                                  const int* __restrict__ mask,
                                                  float* __restrict__ out) {
    const int t = threadIdx.x;
    const f4* __restrict__ P4 = (const f4*)P;
    const f4* __restrict__ S4 = (const f4*)S;
    f4* __restrict__ out4 = (f4*)out;

    for (int row = blockIdx.x; row < NVROWS; row += NBLK) {
        if (row < NROWS) {
            const int bc = row / 5;
            const int which = row - bc * 5;
            const int b = bc / NC;
            const int c = bc - b * NC;
            // decode candidate c -> (start i, span s)
            int i, s;
            if (c < 3856) {
                i = c >> 4;
                s = c & 15;
            } else {
                const int r = c - 3856;
                int u = 0, off = 0;
                while (off + (15 - u) <= r) { off += 15 - u; ++u; }
                i = 241 + u;
                s = r - off;
            }
            const int e = i + s;
            const int base = b * LEN;
            f4 v;
            if (which == 0) {  // left excl: P[i-1]
                v = (i > 0) ? P4[(size_t)(base + i - 1) * 192 + t] : (f4)0.f;
            } else if (which == 1) {  // left incl: P[e]
                v = P4[(size_t)(base + e) * 192 + t];
            } else if (which == 2) {  // cand: P[e] - a^(s+1)*P[i-1]
                const f4 pe = P4[(size_t)(base + e) * 192 + t];
                v = pe;
                if (i > 0) v = pe - APOW[s + 1] * P4[(size_t)(base + i - 1) * 192 + t];
            } else if (which == 3) {  // right incl: S[i]
                v = S4[(size_t)(base + i) * 192 + t];
            } else {  // right excl: S[e+1]
                v = (e < LEN - 1) ? S4[(size_t)(base + e + 1) * 192 + t] : (f4)0.f;
            }
            out4[(size_t)row * 192 + t] = v;
        } else {
            // virtual rows: cands_pos + padded_cands for one (b, start i)
            const int r2 = row - NROWS;
            const int b = r2 >> 8;
            const int i = r2 & 255;
            int n, c0;
            if (i <= 240) {
                n = 16;
                c0 = i * 16;
            } else {
                const int r = LEN - i;  // 15..1
                n = r;
                c0 = 3856 + 120 - r * (r + 1) / 2;
            }
            if (t < 64) {  // wave 0 only
                const int m = (t < n) ? mask[b * LEN + i + t] : 0;
                const unsigned long long ball = __ballot(m != 0);
                if (t < n) {
                    const size_t c = (size_t)(b * NC + c0 + t);
                    out[OFF_POS + c * 2] = (float)i;
                    out[OFF_POS + c * 2 + 1] = (float)(i + t);
                    // window [i, i+t]: any mask bit among ballot bits 0..t
                    out[OFF_PAD + c] = (ball & ((2ull << t) - 1)) ? 1.f : 0.f;
                }
            }
        }
    }
}

extern "C" void kernel_launch(void* const* d_in, const int* in_sizes, int n_in,
                              void* d_out, int out_size, void* d_ws, size_t ws_size,
                              hipStream_t stream) {
    const float* x = (const float*)d_in[0];
    const int* mask = (const int*)d_in[1];
    float* out = (float*)d_out;
    float* P = (float*)d_ws;                  // [8][256][768] fp32
    float* S = P + (size_t)NB * LEN * DIM;    // [8][256][768] fp32  (12.6 MB total)

    scan_kernel<<<dim3(DIM / 32, NB, 2), 256, 0, stream>>>(x, P, S);
    row_kernel<<<NBLK, 192, 0, stream>>>(P, S, mask, out);
}